// Round 1
// baseline (241.926 us; speedup 1.0000x reference)
//
#include <hip/hip_runtime.h>
#include <math.h>

// Problem constants (from reference): B=16, N=1024, C_IN=256, C_OUT=256, POOL_RATIO=0.5
#define Bsz 16
#define Nn  1024
#define Cin 256
#define Cout 256

// d_out layout (float32, concatenated): x_out[16,1024,256], adj_out[16,1024,1024],
// new_mask[16,1024], new_n_nodes[16]
#define XOUT_OFF   0
#define ADJ_OFF    (16*1024*256)                 // 4,194,304
#define MASK_OFF   (ADJ_OFF + 16*1024*1024)      // 20,971,520
#define NN_OFF     (MASK_OFF + 16*1024)          // 20,987,904

// Scratch lives inside the adj_out region (overwritten last by k_adjout):
//   H  at ADJ+0          (4,194,304 floats)
//   XW at ADJ+4,194,304  (4,194,304 floats)
//   Y  at ADJ+8,388,608  (16,384 floats)
//   INVN at ADJ+8,404,992 (1 float)

// ---------------- inv_norm of pooling vector ----------------
__global__ __launch_bounds__(256) void k_invnorm(const float* __restrict__ pool,
                                                 float* __restrict__ invn) {
    int t = threadIdx.x;
    float v = pool[t];
    v *= v;
    for (int off = 32; off > 0; off >>= 1) v += __shfl_down(v, off, 64);
    __shared__ float part[4];
    if ((t & 63) == 0) part[t >> 6] = v;
    __syncthreads();
    if (t == 0) invn[0] = 1.0f / sqrtf(part[0] + part[1] + part[2] + part[3]);
}

// ---------------- xw = x @ W  (fp32 tiled GEMM, 64x64 tile, 4x4/thread) ----------------
__global__ __launch_bounds__(256) void k_xw(const float* __restrict__ X,
                                            const float* __restrict__ W,
                                            float* __restrict__ XW) {
    const int K = 256, Nc = 256;
    int bx = blockIdx.x & 3;        // 4 col blocks of 64
    int by = blockIdx.x >> 2;       // 256 row blocks of 64
    int rowBase = by * 64;
    int colBase = bx * 64;
    int tid = threadIdx.x;

    __shared__ float As[16][64];    // [k][m] transposed for fragment reads
    __shared__ float Bs[16][64];    // [k][n]

    int m0 = (tid & 15) * 4;        // micro-tile rows
    int n0 = (tid >> 4) * 4;        // micro-tile cols

    float acc[4][4];
    #pragma unroll
    for (int i = 0; i < 4; ++i)
        #pragma unroll
        for (int j = 0; j < 4; ++j) acc[i][j] = 0.0f;

    int lm = tid >> 2;              // 0..63  row within A tile
    int lk = (tid & 3) * 4;         // 0,4,8,12 k within tile (float4)
    int bk = tid >> 4;              // 0..15 k row within B tile
    int bn = (tid & 15) * 4;        // float4 col within B tile

    for (int kt = 0; kt < K / 16; ++kt) {
        __syncthreads();
        float4 av = *(const float4*)&X[(size_t)(rowBase + lm) * K + kt * 16 + lk];
        As[lk + 0][lm] = av.x;
        As[lk + 1][lm] = av.y;
        As[lk + 2][lm] = av.z;
        As[lk + 3][lm] = av.w;
        float4 bv = *(const float4*)&W[(size_t)(kt * 16 + bk) * Nc + colBase + bn];
        *(float4*)&Bs[bk][bn] = bv;
        __syncthreads();

        #pragma unroll
        for (int kk = 0; kk < 16; ++kk) {
            float4 a = *(const float4*)&As[kk][m0];
            float4 b = *(const float4*)&Bs[kk][n0];
            float ar[4] = {a.x, a.y, a.z, a.w};
            float br[4] = {b.x, b.y, b.z, b.w};
            #pragma unroll
            for (int i = 0; i < 4; ++i)
                #pragma unroll
                for (int j = 0; j < 4; ++j)
                    acc[i][j] = fmaf(ar[i], br[j], acc[i][j]);
        }
    }

    #pragma unroll
    for (int i = 0; i < 4; ++i) {
        float4 o = make_float4(acc[i][0], acc[i][1], acc[i][2], acc[i][3]);
        *(float4*)&XW[(size_t)(rowBase + m0 + i) * Nc + colBase + n0] = o;
    }
}

// ---------------- h = adj @ xw + b (sparse row gather) ; y_raw = h . pool ----------------
__global__ __launch_bounds__(256) void k_spmm(const float* __restrict__ adj,
                                              const float* __restrict__ XW,
                                              const float* __restrict__ bias,
                                              const float* __restrict__ pool,
                                              float* __restrict__ H,
                                              float* __restrict__ Y) {
    __shared__ float sAdj[1024];
    __shared__ int   sIdx[1024];
    __shared__ int   sCnt;
    __shared__ float sPart[4];

    int row = blockIdx.x;                 // b*1024 + n
    int b   = row >> 10;
    int tid = threadIdx.x;
    if (tid == 0) sCnt = 0;
    __syncthreads();

    float4 a4 = ((const float4*)(adj + (size_t)row * 1024))[tid];
    *(float4*)&sAdj[tid * 4] = a4;

    float av[4] = {a4.x, a4.y, a4.z, a4.w};
    #pragma unroll
    for (int i = 0; i < 4; ++i) {
        if (av[i] != 0.0f) {
            int p = atomicAdd(&sCnt, 1);
            sIdx[p] = tid * 4 + i;
        }
    }
    __syncthreads();

    int cnt = sCnt;
    float acc = bias[tid];
    const float* xwb = XW + (size_t)b * Nn * Cout + tid;
    for (int j = 0; j < cnt; ++j) {
        int m = sIdx[j];
        acc = fmaf(sAdj[m], xwb[(size_t)m * Cout], acc);
    }
    H[(size_t)row * Cout + tid] = acc;

    float val = acc * pool[tid];
    for (int off = 32; off > 0; off >>= 1) val += __shfl_down(val, off, 64);
    if ((tid & 63) == 0) sPart[tid >> 6] = val;
    __syncthreads();
    if (tid == 0) Y[row] = sPart[0] + sPart[1] + sPart[2] + sPart[3];
}

// ---------------- per-batch: stable ascending argsort of y, pooling mask ----------------
__global__ __launch_bounds__(1024) void k_sortmask(const float* __restrict__ Y,
                                                   const int* __restrict__ maskIn,
                                                   const int* __restrict__ nNodes,
                                                   float* __restrict__ newMask,
                                                   float* __restrict__ newN) {
    __shared__ float key[1024];
    __shared__ int   kidx[1024];
    __shared__ int   sm[1024];

    int b = blockIdx.x;
    int t = threadIdx.x;
    key[t]  = Y[b * Nn + t];
    kidx[t] = t;
    __syncthreads();

    // bitonic sort ascending, tie-break on original index (== stable argsort)
    for (int k = 2; k <= 1024; k <<= 1) {
        for (int j = k >> 1; j > 0; j >>= 1) {
            int partner = t ^ j;
            if (partner > t) {
                bool dirAsc = ((t & k) == 0);
                float ka = key[t], kb = key[partner];
                int   ia = kidx[t], ib = kidx[partner];
                bool aGreater = (ka > kb) || (ka == kb && ia > ib);
                if (aGreater == dirAsc) {
                    key[t] = kb; key[partner] = ka;
                    kidx[t] = ib; kidx[partner] = ia;
                }
            }
            __syncthreads();
        }
    }

    int mval = maskIn[b * Nn + kidx[t]];
    sm[t] = mval;
    __syncthreads();

    // inclusive scan (Hillis-Steele)
    for (int off = 1; off < 1024; off <<= 1) {
        int add = (t >= off) ? sm[t - off] : 0;
        __syncthreads();
        sm[t] += add;
        __syncthreads();
    }

    int rank = sm[t] - mval;                      // exclusive rank among masked
    int nrem = (int)((float)nNodes[b] * 0.5f);    // (1 - POOL_RATIO) = 0.5
    int nm   = (mval == 1 && rank < nrem) ? 0 : mval;
    newMask[b * Nn + kidx[t]] = (float)nm;
    if (t == 0) newN[b] = (float)(nNodes[b] - nrem);
}

// ---------------- x_out = h * tanh(y*invnorm) * mask ----------------
__global__ __launch_bounds__(256) void k_xout(const float* __restrict__ H,
                                              const float* __restrict__ Y,
                                              const float* __restrict__ invn,
                                              const float* __restrict__ mf,
                                              float* __restrict__ XO) {
    int i = blockIdx.x * 256 + threadIdx.x;       // float4 index, total 1,048,576
    if (i >= Bsz * Nn * (Cout / 4)) return;
    int row = i >> 6;                             // /(256/4)
    float s = tanhf(Y[row] * invn[0]) * mf[row];
    float4 h4 = ((const float4*)H)[i];
    h4.x *= s; h4.y *= s; h4.z *= s; h4.w *= s;
    ((float4*)XO)[i] = h4;
}

// ---------------- adj_out = mf_i * adj * mf_j ----------------
__global__ __launch_bounds__(256) void k_adjout(const float* __restrict__ adj,
                                                const float* __restrict__ mf,
                                                float* __restrict__ AO) {
    int i = blockIdx.x * 256 + threadIdx.x;       // float4 index, total 4,194,304
    int b   = i >> 18;                            // 1024*1024/4 = 262144
    int rem = i & 262143;
    int r   = rem >> 8;                           // row within batch
    int j4  = (rem & 255) << 2;                   // starting col
    const float* mrow = mf + b * Nn;
    float mi = mrow[r];
    float4 a4 = ((const float4*)adj)[i];
    float4 m4 = *(const float4*)&mrow[j4];
    float4 o;
    o.x = a4.x * mi * m4.x;
    o.y = a4.y * mi * m4.y;
    o.z = a4.z * mi * m4.z;
    o.w = a4.w * mi * m4.w;
    ((float4*)AO)[i] = o;
}

extern "C" void kernel_launch(void* const* d_in, const int* in_sizes, int n_in,
                              void* d_out, int out_size, void* d_ws, size_t ws_size,
                              hipStream_t stream) {
    const float* x      = (const float*)d_in[0];
    const float* adj    = (const float*)d_in[1];
    const int*   mask   = (const int*)d_in[2];
    const int*   nnodes = (const int*)d_in[3];
    const float* W      = (const float*)d_in[4];
    const float* bias   = (const float*)d_in[5];
    const float* pool   = (const float*)d_in[6];

    float* out = (float*)d_out;
    float* XO   = out + XOUT_OFF;
    float* AO   = out + ADJ_OFF;
    float* NM   = out + MASK_OFF;
    float* NNo  = out + NN_OFF;

    // scratch inside adj_out region (overwritten last)
    float* H    = AO;
    float* XW   = AO + 4194304;
    float* Y    = AO + 8388608;
    float* INVN = AO + 8404992;

    k_invnorm<<<1, 256, 0, stream>>>(pool, INVN);
    k_xw<<<1024, 256, 0, stream>>>(x, W, XW);
    k_spmm<<<Bsz * Nn, 256, 0, stream>>>(adj, XW, bias, pool, H, Y);
    k_sortmask<<<Bsz, 1024, 0, stream>>>(Y, mask, nnodes, NM, NNo);
    k_xout<<<(Bsz * Nn * Cout / 4 + 255) / 256, 256, 0, stream>>>(H, Y, INVN, NM, XO);
    k_adjout<<<(Bsz * Nn * Nn / 4 + 255) / 256, 256, 0, stream>>>(adj, NM, AO);
}